// Round 18
// baseline (639.604 us; speedup 1.0000x reference)
//
#include <hip/hip_runtime.h>

// Problem constants
#define N_ROWS 32768   // 8*4096
#define DIM    256
#define KCODES 8192
#define DECAYF 0.8f
#define OMDF   0.2f
#define EPSF   1e-5f

// d_out layout (float element offsets)
#define Q_OFF    0
#define IND_OFF  8388608
#define CS_OFF   8421376
#define EA_OFF   8429568
#define NE_OFF   10526720

// Scratch: Xp -> Q first half; rowlist -> Q second half; gbest -> EA head;
// Ep -> EA + 65536 floats. Same proven placement as r10-r17.

// ws layout: e2 f32[8192], cnt i32[8192], start i32[8192], cursor i32[8192],
// sum f32[1]
#define WS_E2    0
#define WS_CNT   8192
#define WS_START 16384
#define WS_CUR   24576
#define WS_SUM   40960

typedef _Float16 half8 __attribute__((ext_vector_type(8)));
typedef float floatx16 __attribute__((ext_vector_type(16)));

#define GLOAD16(g, l) __builtin_amdgcn_global_load_lds( \
    (const __attribute__((address_space(1))) void*)(g), \
    (__attribute__((address_space(3))) void*)(l), 16, 0, 0)

// ---------------------------------------------------------------------------
// prep_all (r10-verified, unchanged)
#define PREP_ROWS 32
__global__ void prep_all_kernel(const float* __restrict__ x,
                                const float* __restrict__ embed,
                                const float* __restrict__ cs,
                                _Float16* __restrict__ Xp,
                                _Float16* __restrict__ Ep,
                                float* __restrict__ out,
                                float* __restrict__ ws) {
  __shared__ __align__(16) _Float16 L[PREP_ROWS][264];
  __shared__ float red[4];
  const int t = threadIdx.x;
  const int bid = blockIdx.x;

  if (bid < 1024) {
    if (bid < 128) {
      unsigned long long* gbest = (unsigned long long*)(out + EA_OFF);
      gbest[bid * 256 + t] = 0ULL;
    } else if (bid < 160) {
      ((int*)(ws + WS_CNT))[(bid - 128) * 256 + t] = 0;
    }
    const int row0 = bid * PREP_ROWS;
    #pragma unroll
    for (int it = 0; it < 8; ++it) {
      int idx = it * 256 + t;
      int r = idx >> 6, q = idx & 63;
      float4 v = *(const float4*)&x[(size_t)(row0 + r) * DIM + q * 4];
      L[r][q * 4 + 0] = (_Float16)v.x;
      L[r][q * 4 + 1] = (_Float16)v.y;
      L[r][q * 4 + 2] = (_Float16)v.z;
      L[r][q * 4 + 3] = (_Float16)v.w;
    }
    __syncthreads();
    #pragma unroll
    for (int it = 0; it < 4; ++it) {
      int idx = it * 256 + t;
      int slot = idx >> 5, r = idx & 31;
      *(float4*)&Xp[((size_t)slot * N_ROWS + row0 + r) * 8] =
          *(const float4*)&L[r][slot * 8];
    }
  } else {
    const int row0 = (bid - 1024) * PREP_ROWS;
    float* e2 = ws + WS_E2;
    #pragma unroll
    for (int it = 0; it < 8; ++it) {
      int idx = it * 256 + t;
      int r = idx >> 6, q = idx & 63;
      float4 v = *(const float4*)&embed[(size_t)(row0 + r) * DIM + q * 4];
      L[r][q * 4 + 0] = (_Float16)v.x;
      L[r][q * 4 + 1] = (_Float16)v.y;
      L[r][q * 4 + 2] = (_Float16)v.z;
      L[r][q * 4 + 3] = (_Float16)v.w;
      float ssq = v.x * v.x + v.y * v.y + v.z * v.z + v.w * v.w;
      #pragma unroll
      for (int o = 32; o; o >>= 1) ssq += __shfl_xor(ssq, o);
      if ((t & 63) == 0) e2[row0 + r] = ssq;
    }
    if (bid == 1024) {
      float s = 0.0f;
      for (int j = t; j < KCODES; j += 256) s += cs[j];
      #pragma unroll
      for (int o = 32; o; o >>= 1) s += __shfl_xor(s, o);
      if ((t & 63) == 0) red[t >> 6] = s;
    }
    __syncthreads();
    if (bid == 1024 && t == 0)
      ws[WS_SUM] = red[0] + red[1] + red[2] + red[3];
    #pragma unroll
    for (int it = 0; it < 4; ++it) {
      int idx = it * 256 + t;
      int slot = idx >> 5, r = idx & 31;
      *(float4*)&Ep[((size_t)slot * KCODES + row0 + r) * 8] =
          *(const float4*)&L[r][slot * 8];
    }
  }
}

// ---------------------------------------------------------------------------
// Main MFMA kernel — A-RESIDENT LDS + STREAMING-B, ZERO-BARRIER main loop.
// The block's full A panel (256 codes x K=256 f16 = 128 KB) is loaded into
// LDS ONCE (global_load_lds burst + single barrier). Then each wave runs an
// independent pipeline over 16 row-tiles: per K16-step, 4 ds_read_b128
// A-frags (conflict-free, r13 pattern) + 2 register B-loads from Xp (L2,
// 4x multicast per XCD) + 8 MFMAs, register double-buffered, fully
// unrolled. No s_barrier / no manual vmcnt in the loop; no A re-staging
// (16x reuse); no LDS writes in the loop.
// Block 256 codes x 256 rows/tile, 8 waves (2Mx4N), wave tile 128x64.
// Grid 256 = 1 block/CU (r14 mapping, FETCH-friendly).
__global__ __launch_bounds__(512, 2) void main_kernel(
    const _Float16* __restrict__ Xp, const _Float16* __restrict__ Ep,
    const float* __restrict__ e2, unsigned long long* __restrict__ gbest) {
  __shared__ __align__(16) _Float16 As[32 * 256 * 8];  // [slot][code][8] 128KB
  __shared__ __align__(16) float e2s[256];             // 1KB

  const int t = threadIdx.x;
  const int w = t >> 6;
  const int lane = t & 63;
  const int l31 = lane & 31;
  const int h = lane >> 5;
  const int wm = w >> 2;   // code half 0..1
  const int wn = w & 3;    // row quarter 0..3

  // 256 blocks: xcd = bid&7 owns cb in [4*xcd,4*xcd+4); 8 row groups.
  const int bid = blockIdx.x;
  const int bi = bid >> 3;                   // 0..31
  const int cb = (bid & 7) * 4 + (bi >> 3);  // 0..31
  const int rbg = bi & 7;                    // 0..7
  const int codes0 = cb * 256;
  const int rowbase = rbg * 4096;            // 16 row-tiles of 256

  // ---- one-time A panel load: 32 slots x 256 codes x 16B, 16 iters
  #pragma unroll
  for (int it = 0; it < 16; ++it) {
    const int idx = it * 512 + t;
    const int slot = idx >> 8;
    const int code = idx & 255;
    GLOAD16(Ep + ((size_t)slot * KCODES + codes0 + code) * 8,
            &As[(slot * 256 + code) * 8]);
  }
  if (t < 64) {
    float4 v = *(const float4*)&e2[codes0 + t * 4];
    *(float4*)&e2s[t * 4] = v;
  }
  asm volatile("s_waitcnt vmcnt(0) lgkmcnt(0)" ::: "memory");
  __builtin_amdgcn_s_barrier();
  __builtin_amdgcn_sched_barrier(0);

  // A-frag LDS base (bytes handled via f16 indices): for step j, parity h:
  // slot = 2*j + h; addr = ((slot*256) + wm*128 + ct*32 + l31) * 8
  const int aIdx = (h * 256 + wm * 128 + l31) * 8;

  floatx16 acc[4][2];

  #pragma unroll 1
  for (int tile = 0; tile < 16; ++tile) {
    const int rows0 = rowbase + tile * 256;
    const _Float16* bB =
        Xp + ((size_t)h * N_ROWS + rows0 + wn * 64 + l31) * 8;

    // acc init = -0.5*e2 from LDS stash
    #pragma unroll
    for (int ct = 0; ct < 4; ++ct) {
      const int cl = wm * 128 + ct * 32 + 4 * h;
      #pragma unroll
      for (int rq = 0; rq < 4; ++rq) {
        float4 v = *(const float4*)&e2s[cl + rq * 8];
        acc[ct][0][rq * 4 + 0] = -0.5f * v.x;
        acc[ct][0][rq * 4 + 1] = -0.5f * v.y;
        acc[ct][0][rq * 4 + 2] = -0.5f * v.z;
        acc[ct][0][rq * 4 + 3] = -0.5f * v.w;
      }
      acc[ct][1] = acc[ct][0];
    }

    // register double-buffer, prefetch step 0
    half8 A[2][4], B[2][2];
    #pragma unroll
    for (int ct = 0; ct < 4; ++ct)
      A[0][ct] = *(const half8*)&As[aIdx + ct * 32 * 8];
    B[0][0] = *(const half8*)(bB);
    B[0][1] = *(const half8*)(bB + 32 * 8);

    #pragma unroll
    for (int j = 0; j < 16; ++j) {
      const int p = j & 1;
      const int q = p ^ 1;
      if (j < 15) {  // prefetch step j+1
        const int sOff = (2 * (j + 1)) * 256 * 8;  // slot stride
        #pragma unroll
        for (int ct = 0; ct < 4; ++ct)
          A[q][ct] = *(const half8*)&As[aIdx + sOff + ct * 32 * 8];
        const size_t gOff = (size_t)(2 * (j + 1)) * N_ROWS * 8;
        B[q][0] = *(const half8*)(bB + gOff);
        B[q][1] = *(const half8*)(bB + gOff + 32 * 8);
      }
      __builtin_amdgcn_s_setprio(1);
      acc[0][0] = __builtin_amdgcn_mfma_f32_32x32x16_f16(A[p][0], B[p][0], acc[0][0], 0, 0, 0);
      acc[0][1] = __builtin_amdgcn_mfma_f32_32x32x16_f16(A[p][0], B[p][1], acc[0][1], 0, 0, 0);
      acc[1][0] = __builtin_amdgcn_mfma_f32_32x32x16_f16(A[p][1], B[p][0], acc[1][0], 0, 0, 0);
      acc[1][1] = __builtin_amdgcn_mfma_f32_32x32x16_f16(A[p][1], B[p][1], acc[1][1], 0, 0, 0);
      acc[2][0] = __builtin_amdgcn_mfma_f32_32x32x16_f16(A[p][2], B[p][0], acc[2][0], 0, 0, 0);
      acc[2][1] = __builtin_amdgcn_mfma_f32_32x32x16_f16(A[p][2], B[p][1], acc[2][1], 0, 0, 0);
      acc[3][0] = __builtin_amdgcn_mfma_f32_32x32x16_f16(A[p][3], B[p][0], acc[3][0], 0, 0, 0);
      acc[3][1] = __builtin_amdgcn_mfma_f32_32x32x16_f16(A[p][3], B[p][1], acc[3][1], 0, 0, 0);
      __builtin_amdgcn_s_setprio(0);
    }

    // tile epilogue: lane argmax -> h-pair shfl -> atomicMax
    // C layout (32x32): col(xrow)=lane&31, row(code)=(r&3)+8*(r>>2)+4*h
    #pragma unroll
    for (int rt = 0; rt < 2; ++rt) {
      float best = -3.0e38f;
      int bidx = 0;
      #pragma unroll
      for (int ct = 0; ct < 4; ++ct) {
        const int cbase = codes0 + wm * 128 + ct * 32 + 4 * h;
        #pragma unroll
        for (int r = 0; r < 16; ++r) {
          const int code = cbase + (r & 3) + 8 * (r >> 2);
          float v = acc[ct][rt][r];
          if (v > best || (v == best && code < bidx)) { best = v; bidx = code; }
        }
      }
      unsigned u = __float_as_uint(best);
      u = (u & 0x80000000u) ? ~u : (u | 0x80000000u);
      unsigned long long p =
          ((unsigned long long)u << 32) | (unsigned)(8191 - bidx);
      unsigned long long op = (unsigned long long)__shfl_xor((long long)p, 32);
      if (op > p) p = op;
      if (h == 0)
        atomicMax(&gbest[rows0 + wn * 64 + rt * 32 + l31], p);
    }
  }
}

// ---------------------------------------------------------------------------
// decode_count: gbest -> IND + cnt histogram. Last reader of gbest.
__global__ void decode_count_kernel(const unsigned long long* __restrict__ gbest,
                                    float* __restrict__ out,
                                    int* __restrict__ cnt) {
  int r = blockIdx.x * blockDim.x + threadIdx.x;  // 32768 threads
  unsigned long long p = gbest[r];
  int k = 8191 - (int)(unsigned)(p & 0xFFFFFFFFull);
  out[IND_OFF + r] = (float)k;
  atomicAdd(&cnt[k], 1);
}

// ---------------------------------------------------------------------------
__global__ void prefix_kernel(const int* __restrict__ cnt,
                              int* __restrict__ start,
                              int* __restrict__ cursor) {
  __shared__ int part[1024];
  const int t = threadIdx.x;
  int loc[8];
  int s = 0;
  #pragma unroll
  for (int j = 0; j < 8; ++j) { loc[j] = cnt[t * 8 + j]; s += loc[j]; }
  part[t] = s;
  __syncthreads();
  for (int off = 1; off < 1024; off <<= 1) {
    int v = (t >= off) ? part[t - off] : 0;
    __syncthreads();
    part[t] += v;
    __syncthreads();
  }
  int base = part[t] - s;
  #pragma unroll
  for (int j = 0; j < 8; ++j) {
    start[t * 8 + j] = base;
    cursor[t * 8 + j] = base;
    base += loc[j];
  }
}

// ---------------------------------------------------------------------------
__global__ void scatter_rows_kernel(const float* __restrict__ out,
                                    int* __restrict__ cursor,
                                    int* __restrict__ rowlist) {
  int r = blockIdx.x * blockDim.x + threadIdx.x;  // 32768 threads
  int k = (int)out[IND_OFF + r];
  int pos = atomicAdd(&cursor[k], 1);
  rowlist[pos] = r;
}

// ---------------------------------------------------------------------------
__global__ void bucket_final_kernel(const float* __restrict__ x,
                                    const float* __restrict__ cs,
                                    const float* __restrict__ embed_avg,
                                    const int* __restrict__ start,
                                    const int* __restrict__ cnt,
                                    const int* __restrict__ rowlist,
                                    float* __restrict__ out,
                                    const float* __restrict__ ws_sum) {
  const int lane = threadIdx.x & 63;
  const int k = blockIdx.x * 4 + (threadIdx.x >> 6);
  const int s = start[k];
  const int n = cnt[k];
  float4 acc = make_float4(0.f, 0.f, 0.f, 0.f);
  int i = 0;
  for (; i + 2 <= n; i += 2) {
    int r0 = rowlist[s + i];
    int r1 = rowlist[s + i + 1];
    float4 v0 = *(const float4*)&x[(size_t)r0 * DIM + lane * 4];
    float4 v1 = *(const float4*)&x[(size_t)r1 * DIM + lane * 4];
    acc.x += v0.x + v1.x; acc.y += v0.y + v1.y;
    acc.z += v0.z + v1.z; acc.w += v0.w + v1.w;
  }
  if (i < n) {
    int r0 = rowlist[s + i];
    float4 v0 = *(const float4*)&x[(size_t)r0 * DIM + lane * 4];
    acc.x += v0.x; acc.y += v0.y; acc.z += v0.z; acc.w += v0.w;
  }
  const float S = DECAYF * (*ws_sum) + OMDF * (float)N_ROWS;
  const float scale = S / (S + (float)KCODES * EPSF);
  float ncs = cs[k] * DECAYF + (float)n * OMDF;
  if (lane == 0) out[CS_OFF + k] = ncs;
  float4 ea = *(const float4*)&embed_avg[(size_t)k * DIM + lane * 4];
  float4 nea;
  nea.x = ea.x * DECAYF + acc.x * OMDF;
  nea.y = ea.y * DECAYF + acc.y * OMDF;
  nea.z = ea.z * DECAYF + acc.z * OMDF;
  nea.w = ea.w * DECAYF + acc.w * OMDF;
  *(float4*)&out[EA_OFF + (size_t)k * DIM + lane * 4] = nea;
  float inv_sm = 1.0f / ((ncs + EPSF) * scale);
  float4 ne;
  ne.x = nea.x * inv_sm;
  ne.y = nea.y * inv_sm;
  ne.z = nea.z * inv_sm;
  ne.w = nea.w * inv_sm;
  *(float4*)&out[NE_OFF + (size_t)k * DIM + lane * 4] = ne;
}

// ---------------------------------------------------------------------------
__global__ void finish_q_kernel(const float* __restrict__ embed,
                                float* __restrict__ out) {
  const int lane = threadIdx.x & 63;
  const int wave = (blockIdx.x * blockDim.x + threadIdx.x) >> 6;  // 0..2047
  for (int row = wave; row < N_ROWS; row += 2048) {
    int k = (int)out[IND_OFF + row];
    float4 ev = *(const float4*)&embed[(size_t)k * DIM + lane * 4];
    *(float4*)&out[Q_OFF + (size_t)row * DIM + lane * 4] = ev;
  }
}

// ---------------------------------------------------------------------------
extern "C" void kernel_launch(void* const* d_in, const int* in_sizes, int n_in,
                              void* d_out, int out_size, void* d_ws, size_t ws_size,
                              hipStream_t stream) {
  const float* x = (const float*)d_in[0];
  const float* embed = (const float*)d_in[1];
  const float* cs = (const float*)d_in[2];
  const float* ea = (const float*)d_in[3];
  float* out = (float*)d_out;
  float* ws = (float*)d_ws;

  float* e2 = ws + WS_E2;
  int* cnt = (int*)(ws + WS_CNT);
  int* start = (int*)(ws + WS_START);
  int* cursor = (int*)(ws + WS_CUR);
  float* ws_sum = ws + WS_SUM;

  _Float16* Xp = (_Float16*)(out + Q_OFF);                          // 16 MB
  int* rowlist = (int*)(out + Q_OFF + 4194304);                     // Q dead half
  unsigned long long* gbest = (unsigned long long*)(out + EA_OFF);  // 256 KB
  _Float16* Ep = (_Float16*)(out + EA_OFF + 65536);                 // 4 MB

  prep_all_kernel<<<1280, 256, 0, stream>>>(x, embed, cs, Xp, Ep, out, ws);
  main_kernel<<<256, 512, 0, stream>>>(Xp, Ep, e2, gbest);
  decode_count_kernel<<<128, 256, 0, stream>>>(gbest, out, cnt);
  prefix_kernel<<<1, 1024, 0, stream>>>(cnt, start, cursor);
  scatter_rows_kernel<<<128, 256, 0, stream>>>(out, cursor, rowlist);
  bucket_final_kernel<<<2048, 256, 0, stream>>>(x, cs, ea, start, cnt,
                                                rowlist, out, ws_sum);
  finish_q_kernel<<<512, 256, 0, stream>>>(embed, out);
}

// Round 19
// 378.460 us; speedup vs baseline: 1.6900x; 1.6900x over previous
//
#include <hip/hip_runtime.h>

// Problem constants
#define N_ROWS 32768   // 8*4096
#define DIM    256
#define KCODES 8192
#define DECAYF 0.8f
#define OMDF   0.2f
#define EPSF   1e-5f

// d_out layout (float element offsets)
#define Q_OFF    0
#define IND_OFF  8388608
#define CS_OFF   8421376
#define EA_OFF   8429568
#define NE_OFF   10526720

// Scratch: Xp -> Q first half; rowlist -> Q second half; gbest -> EA head;
// Ep -> EA + 65536 floats. Proven placement (r10-r13).

// ws layout: e2 f32[8192], cnt i32[8192], start i32[8192], cursor i32[8192],
// sum f32[1]
#define WS_E2    0
#define WS_CNT   8192
#define WS_START 16384
#define WS_CUR   24576
#define WS_SUM   40960

typedef _Float16 half8 __attribute__((ext_vector_type(8)));
typedef float floatx16 __attribute__((ext_vector_type(16)));

#define GLOAD16(g, l) __builtin_amdgcn_global_load_lds( \
    (const __attribute__((address_space(1))) void*)(g), \
    (__attribute__((address_space(3))) void*)(l), 16, 0, 0)

// ---------------------------------------------------------------------------
// prep_all: blocks 0..1023 = prep_x (+ zero gbest/cnt); 1024..1279 = prep_e
// (+ block 1024 reduces sum(cluster_size) into ws_sum).
#define PREP_ROWS 32
__global__ void prep_all_kernel(const float* __restrict__ x,
                                const float* __restrict__ embed,
                                const float* __restrict__ cs,
                                _Float16* __restrict__ Xp,
                                _Float16* __restrict__ Ep,
                                float* __restrict__ out,
                                float* __restrict__ ws) {
  __shared__ __align__(16) _Float16 L[PREP_ROWS][264];
  __shared__ float red[4];
  const int t = threadIdx.x;
  const int bid = blockIdx.x;

  if (bid < 1024) {
    if (bid < 128) {
      unsigned long long* gbest = (unsigned long long*)(out + EA_OFF);
      gbest[bid * 256 + t] = 0ULL;
    } else if (bid < 160) {
      ((int*)(ws + WS_CNT))[(bid - 128) * 256 + t] = 0;
    }
    const int row0 = bid * PREP_ROWS;
    #pragma unroll
    for (int it = 0; it < 8; ++it) {
      int idx = it * 256 + t;
      int r = idx >> 6, q = idx & 63;
      float4 v = *(const float4*)&x[(size_t)(row0 + r) * DIM + q * 4];
      L[r][q * 4 + 0] = (_Float16)v.x;
      L[r][q * 4 + 1] = (_Float16)v.y;
      L[r][q * 4 + 2] = (_Float16)v.z;
      L[r][q * 4 + 3] = (_Float16)v.w;
    }
    __syncthreads();
    #pragma unroll
    for (int it = 0; it < 4; ++it) {
      int idx = it * 256 + t;
      int slot = idx >> 5, r = idx & 31;
      *(float4*)&Xp[((size_t)slot * N_ROWS + row0 + r) * 8] =
          *(const float4*)&L[r][slot * 8];
    }
  } else {
    const int row0 = (bid - 1024) * PREP_ROWS;
    float* e2 = ws + WS_E2;
    #pragma unroll
    for (int it = 0; it < 8; ++it) {
      int idx = it * 256 + t;
      int r = idx >> 6, q = idx & 63;
      float4 v = *(const float4*)&embed[(size_t)(row0 + r) * DIM + q * 4];
      L[r][q * 4 + 0] = (_Float16)v.x;
      L[r][q * 4 + 1] = (_Float16)v.y;
      L[r][q * 4 + 2] = (_Float16)v.z;
      L[r][q * 4 + 3] = (_Float16)v.w;
      float ssq = v.x * v.x + v.y * v.y + v.z * v.z + v.w * v.w;
      #pragma unroll
      for (int o = 32; o; o >>= 1) ssq += __shfl_xor(ssq, o);
      if ((t & 63) == 0) e2[row0 + r] = ssq;
    }
    if (bid == 1024) {
      float s = 0.0f;
      for (int j = t; j < KCODES; j += 256) s += cs[j];
      #pragma unroll
      for (int o = 32; o; o >>= 1) s += __shfl_xor(s, o);
      if ((t & 63) == 0) red[t >> 6] = s;
    }
    __syncthreads();
    if (bid == 1024 && t == 0)
      ws[WS_SUM] = red[0] + red[1] + red[2] + red[3];
    #pragma unroll
    for (int it = 0; it < 4; ++it) {
      int idx = it * 256 + t;
      int slot = idx >> 5, r = idx & 31;
      *(float4*)&Ep[((size_t)slot * KCODES + row0 + r) * 8] =
          *(const float4*)&L[r][slot * 8];
    }
  }
}

// ---------------------------------------------------------------------------
// Main MFMA kernel (r13 — best measured: 231 us). Pure-hi GEMM K=256,
// persistent 4-row-tile pipeline (32 compile-time steps), K-step 32, 4-buffer
// 128KB LDS, 2-step prefetch, counted vmcnt(4), fully unrolled (all LDS
// offsets immediates; global addresses strength-reduced).
__global__ __launch_bounds__(512, 2) void main_kernel(
    const _Float16* __restrict__ Xp, const _Float16* __restrict__ Ep,
    const float* __restrict__ e2, unsigned long long* __restrict__ gbest) {
  __shared__ __align__(16) _Float16 As[4 * 4 * 256 * 8];  // 64KB
  __shared__ __align__(16) _Float16 Bs[4 * 4 * 256 * 8];  // 64KB
  __shared__ __align__(16) float e2s[256];                // 1KB

  const int t = threadIdx.x;
  const int w = t >> 6;
  const int lane = t & 63;
  const int l31 = lane & 31;
  const int h = lane >> 5;
  const int wm = w >> 2;
  const int wn = w & 3;

  const int bid = blockIdx.x;
  const int bi = bid >> 3;                   // 0..127
  const int cb = (bid & 7) * 4 + (bi >> 5);  // 0..31
  const int rbg = bi & 31;                   // 0..31
  const int codes0 = cb * 256;
  const int rowbase = rbg * 1024;            // 4 row-tiles of 256

  const bool isA = (w < 4);
  const int slot = isA ? w : (w - 4);

  // loop-invariant staging bases (per-step offsets are compile-time strides)
  const _Float16* estage = Ep + ((size_t)slot * KCODES + codes0 + lane) * 8;
  const _Float16* xstage = Xp + ((size_t)slot * N_ROWS + rowbase + lane) * 8;
  _Float16* adst = &As[slot * 2048];
  _Float16* bdst = &Bs[slot * 2048];

  auto stage = [&](int s) {  // s compile-time after unroll
    const int buf = s & 3;
    const int se4 = (s & 7) * 4;           // k-slot group base
    if (isA) {
      const _Float16* src = estage + (size_t)se4 * KCODES * 8;
      _Float16* dst = adst + buf * 8192;
      #pragma unroll
      for (int q = 0; q < 4; ++q)
        GLOAD16(src + q * 512, dst + q * 512);
    } else {
      const _Float16* src =
          xstage + (size_t)se4 * N_ROWS * 8 + (size_t)(s >> 3) * 256 * 8;
      _Float16* dst = bdst + buf * 8192;
      #pragma unroll
      for (int q = 0; q < 4; ++q)
        GLOAD16(src + q * 512, dst + q * 512);
    }
  };

  if (t < 64) {
    float4 v = *(const float4*)&e2[codes0 + t * 4];
    *(float4*)&e2s[t * 4] = v;
  }
  __builtin_amdgcn_sched_barrier(0);
  stage(0);
  stage(1);
  asm volatile("s_waitcnt vmcnt(4)" ::: "memory");
  asm volatile("s_waitcnt lgkmcnt(0)" ::: "memory");
  __builtin_amdgcn_s_barrier();
  __builtin_amdgcn_sched_barrier(0);

  floatx16 acc[4][2];
  unsigned long long pbest[4][2];

  #pragma unroll
  for (int tile = 0; tile < 4; ++tile) {
    #pragma unroll
    for (int ct = 0; ct < 4; ++ct) {
      const int cl = wm * 128 + ct * 32 + 4 * h;
      #pragma unroll
      for (int rq = 0; rq < 4; ++rq) {
        float4 v = *(const float4*)&e2s[cl + rq * 8];
        acc[ct][0][rq * 4 + 0] = -0.5f * v.x;
        acc[ct][0][rq * 4 + 1] = -0.5f * v.y;
        acc[ct][0][rq * 4 + 2] = -0.5f * v.z;
        acc[ct][0][rq * 4 + 3] = -0.5f * v.w;
      }
      acc[ct][1] = acc[ct][0];
    }

    #pragma unroll
    for (int i = 0; i < 8; ++i) {
      const int s = tile * 8 + i;
      if (s + 2 < 32) stage(s + 2);
      __builtin_amdgcn_sched_barrier(0);

      const int cur = (s & 3) * 8192;
      #pragma unroll
      for (int ks = 0; ks < 2; ++ks) {
        const int sbase = cur + (2 * ks + h) * 2048;
        half8 a0 = *(const half8*)&As[sbase + (wm * 128 + l31) * 8];
        half8 a1 = *(const half8*)&As[sbase + (wm * 128 + 32 + l31) * 8];
        half8 a2 = *(const half8*)&As[sbase + (wm * 128 + 64 + l31) * 8];
        half8 a3 = *(const half8*)&As[sbase + (wm * 128 + 96 + l31) * 8];
        half8 b0 = *(const half8*)&Bs[sbase + (wn * 64 + l31) * 8];
        half8 b1 = *(const half8*)&Bs[sbase + (wn * 64 + 32 + l31) * 8];
        __builtin_amdgcn_s_setprio(1);
        acc[0][0] = __builtin_amdgcn_mfma_f32_32x32x16_f16(a0, b0, acc[0][0], 0, 0, 0);
        acc[0][1] = __builtin_amdgcn_mfma_f32_32x32x16_f16(a0, b1, acc[0][1], 0, 0, 0);
        acc[1][0] = __builtin_amdgcn_mfma_f32_32x32x16_f16(a1, b0, acc[1][0], 0, 0, 0);
        acc[1][1] = __builtin_amdgcn_mfma_f32_32x32x16_f16(a1, b1, acc[1][1], 0, 0, 0);
        acc[2][0] = __builtin_amdgcn_mfma_f32_32x32x16_f16(a2, b0, acc[2][0], 0, 0, 0);
        acc[2][1] = __builtin_amdgcn_mfma_f32_32x32x16_f16(a2, b1, acc[2][1], 0, 0, 0);
        acc[3][0] = __builtin_amdgcn_mfma_f32_32x32x16_f16(a3, b0, acc[3][0], 0, 0, 0);
        acc[3][1] = __builtin_amdgcn_mfma_f32_32x32x16_f16(a3, b1, acc[3][1], 0, 0, 0);
        __builtin_amdgcn_s_setprio(0);
      }
      __builtin_amdgcn_sched_barrier(0);

      if (s < 31) {
        if (s < 30) {
          asm volatile("s_waitcnt vmcnt(4)" ::: "memory");
        } else {
          asm volatile("s_waitcnt vmcnt(0)" ::: "memory");
        }
        __builtin_amdgcn_s_barrier();
        __builtin_amdgcn_sched_barrier(0);
      }
    }

    #pragma unroll
    for (int rt = 0; rt < 2; ++rt) {
      float best = -3.0e38f;
      int bidx = 0;
      #pragma unroll
      for (int ct = 0; ct < 4; ++ct) {
        const int cbase = codes0 + wm * 128 + ct * 32 + 4 * h;
        #pragma unroll
        for (int r = 0; r < 16; ++r) {
          const int code = cbase + (r & 3) + 8 * (r >> 2);
          float v = acc[ct][rt][r];
          if (v > best || (v == best && code < bidx)) { best = v; bidx = code; }
        }
      }
      unsigned u = __float_as_uint(best);
      u = (u & 0x80000000u) ? ~u : (u | 0x80000000u);
      unsigned long long p =
          ((unsigned long long)u << 32) | (unsigned)(8191 - bidx);
      unsigned long long op = (unsigned long long)__shfl_xor((long long)p, 32);
      if (op > p) p = op;
      pbest[tile][rt] = p;
    }
  }

  #pragma unroll
  for (int tile = 0; tile < 4; ++tile)
    #pragma unroll
    for (int rt = 0; rt < 2; ++rt)
      if (h == 0)
        atomicMax(&gbest[rowbase + tile * 256 + wn * 64 + rt * 32 + l31],
                  pbest[tile][rt]);
}

// ---------------------------------------------------------------------------
// decode_count: gbest -> IND (float) + cnt histogram. Last reader of gbest.
__global__ void decode_count_kernel(const unsigned long long* __restrict__ gbest,
                                    float* __restrict__ out,
                                    int* __restrict__ cnt) {
  int r = blockIdx.x * blockDim.x + threadIdx.x;  // 32768 threads
  unsigned long long p = gbest[r];
  int k = 8191 - (int)(unsigned)(p & 0xFFFFFFFFull);
  out[IND_OFF + r] = (float)k;
  atomicAdd(&cnt[k], 1);
}

// ---------------------------------------------------------------------------
// prefix: one block, exclusive prefix sum of cnt[8192] -> start & cursor.
__global__ void prefix_kernel(const int* __restrict__ cnt,
                              int* __restrict__ start,
                              int* __restrict__ cursor) {
  __shared__ int part[1024];
  const int t = threadIdx.x;
  int loc[8];
  int s = 0;
  #pragma unroll
  for (int j = 0; j < 8; ++j) { loc[j] = cnt[t * 8 + j]; s += loc[j]; }
  part[t] = s;
  __syncthreads();
  for (int off = 1; off < 1024; off <<= 1) {
    int v = (t >= off) ? part[t - off] : 0;
    __syncthreads();
    part[t] += v;
    __syncthreads();
  }
  int base = part[t] - s;  // exclusive base for this thread's 8 codes
  #pragma unroll
  for (int j = 0; j < 8; ++j) {
    start[t * 8 + j] = base;
    cursor[t * 8 + j] = base;
    base += loc[j];
  }
}

// ---------------------------------------------------------------------------
// scatter_rows: bucket row ids by code into rowlist (Q region's dead half).
__global__ void scatter_rows_kernel(const float* __restrict__ out,
                                    int* __restrict__ cursor,
                                    int* __restrict__ rowlist) {
  int r = blockIdx.x * blockDim.x + threadIdx.x;  // 32768 threads
  int k = (int)out[IND_OFF + r];
  int pos = atomicAdd(&cursor[k], 1);
  rowlist[pos] = r;
}

// ---------------------------------------------------------------------------
// bucket_final: one wave per code — non-atomic segment sum of x rows, then
// the FULL epilogue fused: ncs -> CS, nea -> EA, ne -> NE.
__global__ void bucket_final_kernel(const float* __restrict__ x,
                                    const float* __restrict__ cs,
                                    const float* __restrict__ embed_avg,
                                    const int* __restrict__ start,
                                    const int* __restrict__ cnt,
                                    const int* __restrict__ rowlist,
                                    float* __restrict__ out,
                                    const float* __restrict__ ws_sum) {
  const int lane = threadIdx.x & 63;
  const int k = blockIdx.x * 4 + (threadIdx.x >> 6);
  const int s = start[k];
  const int n = cnt[k];
  float4 acc = make_float4(0.f, 0.f, 0.f, 0.f);
  int i = 0;
  for (; i + 2 <= n; i += 2) {
    int r0 = rowlist[s + i];
    int r1 = rowlist[s + i + 1];
    float4 v0 = *(const float4*)&x[(size_t)r0 * DIM + lane * 4];
    float4 v1 = *(const float4*)&x[(size_t)r1 * DIM + lane * 4];
    acc.x += v0.x + v1.x; acc.y += v0.y + v1.y;
    acc.z += v0.z + v1.z; acc.w += v0.w + v1.w;
  }
  if (i < n) {
    int r0 = rowlist[s + i];
    float4 v0 = *(const float4*)&x[(size_t)r0 * DIM + lane * 4];
    acc.x += v0.x; acc.y += v0.y; acc.z += v0.z; acc.w += v0.w;
  }
  const float S = DECAYF * (*ws_sum) + OMDF * (float)N_ROWS;
  const float scale = S / (S + (float)KCODES * EPSF);
  float ncs = cs[k] * DECAYF + (float)n * OMDF;
  if (lane == 0) out[CS_OFF + k] = ncs;
  float4 ea = *(const float4*)&embed_avg[(size_t)k * DIM + lane * 4];
  float4 nea;
  nea.x = ea.x * DECAYF + acc.x * OMDF;
  nea.y = ea.y * DECAYF + acc.y * OMDF;
  nea.z = ea.z * DECAYF + acc.z * OMDF;
  nea.w = ea.w * DECAYF + acc.w * OMDF;
  *(float4*)&out[EA_OFF + (size_t)k * DIM + lane * 4] = nea;
  float inv_sm = 1.0f / ((ncs + EPSF) * scale);
  float4 ne;
  ne.x = nea.x * inv_sm;
  ne.y = nea.y * inv_sm;
  ne.z = nea.z * inv_sm;
  ne.w = nea.w * inv_sm;
  *(float4*)&out[NE_OFF + (size_t)k * DIM + lane * 4] = ne;
}

// ---------------------------------------------------------------------------
// finish_q (runs LAST): quantize gather via IND; overwrites Xp + rowlist.
__global__ void finish_q_kernel(const float* __restrict__ embed,
                                float* __restrict__ out) {
  const int lane = threadIdx.x & 63;
  const int wave = (blockIdx.x * blockDim.x + threadIdx.x) >> 6;  // 0..2047
  for (int row = wave; row < N_ROWS; row += 2048) {
    int k = (int)out[IND_OFF + row];
    float4 ev = *(const float4*)&embed[(size_t)k * DIM + lane * 4];
    *(float4*)&out[Q_OFF + (size_t)row * DIM + lane * 4] = ev;
  }
}

// ---------------------------------------------------------------------------
extern "C" void kernel_launch(void* const* d_in, const int* in_sizes, int n_in,
                              void* d_out, int out_size, void* d_ws, size_t ws_size,
                              hipStream_t stream) {
  const float* x = (const float*)d_in[0];
  const float* embed = (const float*)d_in[1];
  const float* cs = (const float*)d_in[2];
  const float* ea = (const float*)d_in[3];
  float* out = (float*)d_out;
  float* ws = (float*)d_ws;

  float* e2 = ws + WS_E2;
  int* cnt = (int*)(ws + WS_CNT);
  int* start = (int*)(ws + WS_START);
  int* cursor = (int*)(ws + WS_CUR);
  float* ws_sum = ws + WS_SUM;

  _Float16* Xp = (_Float16*)(out + Q_OFF);                          // 16 MB
  int* rowlist = (int*)(out + Q_OFF + 4194304);  // Q dead half (128 KB used)
  unsigned long long* gbest = (unsigned long long*)(out + EA_OFF);  // 256 KB
  _Float16* Ep = (_Float16*)(out + EA_OFF + 65536);                 // 4 MB

  prep_all_kernel<<<1280, 256, 0, stream>>>(x, embed, cs, Xp, Ep, out, ws);
  main_kernel<<<1024, 512, 0, stream>>>(Xp, Ep, e2, gbest);
  decode_count_kernel<<<128, 256, 0, stream>>>(gbest, out, cnt);
  prefix_kernel<<<1, 1024, 0, stream>>>(cnt, start, cursor);
  scatter_rows_kernel<<<128, 256, 0, stream>>>(out, cursor, rowlist);
  bucket_final_kernel<<<2048, 256, 0, stream>>>(x, cs, ea, start, cnt,
                                                rowlist, out, ws_sum);
  finish_q_kernel<<<512, 256, 0, stream>>>(embed, out);
}